// Round 1
// baseline (6993.226 us; speedup 1.0000x reference)
//
#include <hip/hip_runtime.h>

// kNN (K=5, 100 classes): x[4096][512] f32, train[100000][512] f32, labels[100000] i32
// out: predictions[4096] i32.
// Rank by s = t_sq - 2*dot(x,t)  (monotone-equivalent to the reference distance
// per query row; x_sq and sqrt are per-row monotone transforms).

#define N_TEST   4096
#define N_TRAIN  100000
#define DIM      512
#define KNN      5
#define NCH      16
#define CH       6250          // N_TRAIN / NCH
#define BQ       64
#define BT       64
#define BK       16

#define INF 3.402823466e38f

// Insert (d, tg) into sorted top-5 (td ascending). Strict '<' keeps the
// earliest index on ties, matching jax.lax.top_k tie-breaking, given
// candidates are processed in ascending global index order.
__device__ __forceinline__ void ins5(float (&td)[KNN], int (&ti)[KNN], float d, int tg) {
    if (d < td[4]) {
        if (d < td[3]) {
            td[4] = td[3]; ti[4] = ti[3];
            if (d < td[2]) {
                td[3] = td[2]; ti[3] = ti[2];
                if (d < td[1]) {
                    td[2] = td[1]; ti[2] = ti[1];
                    if (d < td[0]) {
                        td[1] = td[0]; ti[1] = ti[0];
                        td[0] = d; ti[0] = tg;
                    } else { td[1] = d; ti[1] = tg; }
                } else { td[2] = d; ti[2] = tg; }
            } else { td[3] = d; ti[3] = tg; }
        } else { td[4] = d; ti[4] = tg; }
    }
}

// ---------------- Phase 0: t_sq[t] = sum_k train[t][k]^2 ----------------
__global__ void tsq_kernel(const float* __restrict__ train, float* __restrict__ tsq) {
    const int lane = threadIdx.x & 63;
    const int wid  = (blockIdx.x * blockDim.x + threadIdx.x) >> 6;
    const int nw   = (gridDim.x * blockDim.x) >> 6;
    for (int row = wid; row < N_TRAIN; row += nw) {
        const float4* p = (const float4*)(train + (size_t)row * DIM);
        float4 a = p[lane];
        float4 b = p[lane + 64];
        float s = a.x*a.x + a.y*a.y + a.z*a.z + a.w*a.w
                + b.x*b.x + b.y*b.y + b.z*b.z + b.w*b.w;
        #pragma unroll
        for (int off = 32; off > 0; off >>= 1) s += __shfl_down(s, off, 64);
        if (lane == 0) tsq[row] = s;
    }
}

// ------- Phase 1: per (query-tile, train-chunk) fused scores + top-5 -------
__global__ __launch_bounds__(256, 4) void knn_partial(
    const float* __restrict__ x, const float* __restrict__ train,
    const float* __restrict__ tsq,
    float* __restrict__ wsd, int* __restrict__ wsi)
{
    __shared__ __align__(16) float xs[BK][BQ];      // transposed: [k][q]
    __shared__ __align__(16) float ts[BK][BT];      // transposed: [k][t]
    __shared__ float sc[BQ][BT + 1];

    const int tid = threadIdx.x;
    const int q0  = blockIdx.x * BQ;
    const int c   = blockIdx.y;
    const int tstart = c * CH;
    const int tend   = tstart + CH;          // CH*NCH == N_TRAIN exactly

    const int ty = tid >> 4;                 // 0..15 -> query group
    const int tx = tid & 15;                 // 0..15 -> train group
    const int lrow = tid >> 2;               // 0..63 loader row
    const int lcol = (tid & 3) << 2;         // 0,4,8,12 loader col group

    const float* xrow = x + (size_t)(q0 + lrow) * DIM + lcol;

    float td[KNN]; int ti[KNN];
    #pragma unroll
    for (int i = 0; i < KNN; ++i) { td[i] = INF; ti[i] = -1; }

    const int nsub = (CH + BT - 1) / BT;     // 98
    for (int st = 0; st < nsub; ++st) {
        const int tb   = tstart + st * BT;
        const int trow = tb + lrow;
        const float* trp = train + (size_t)trow * DIM + lcol;
        const bool tvalid = (trow < N_TRAIN);

        float acc[4][4];
        #pragma unroll
        for (int i = 0; i < 4; ++i)
            #pragma unroll
            for (int j = 0; j < 4; ++j) acc[i][j] = 0.f;

        for (int kt = 0; kt < DIM; kt += BK) {
            const float4 xv = *(const float4*)(xrow + kt);
            const float4 tv = tvalid ? *(const float4*)(trp + kt)
                                     : make_float4(0.f, 0.f, 0.f, 0.f);
            __syncthreads();                 // protect prior tile reads
            xs[lcol + 0][lrow] = xv.x; xs[lcol + 1][lrow] = xv.y;
            xs[lcol + 2][lrow] = xv.z; xs[lcol + 3][lrow] = xv.w;
            ts[lcol + 0][lrow] = tv.x; ts[lcol + 1][lrow] = tv.y;
            ts[lcol + 2][lrow] = tv.z; ts[lcol + 3][lrow] = tv.w;
            __syncthreads();
            #pragma unroll
            for (int k = 0; k < BK; ++k) {
                const float4 a = *(const float4*)&xs[k][ty << 2];
                const float4 b = *(const float4*)&ts[k][tx << 2];
                const float av[4] = {a.x, a.y, a.z, a.w};
                const float bv[4] = {b.x, b.y, b.z, b.w};
                #pragma unroll
                for (int i = 0; i < 4; ++i)
                    #pragma unroll
                    for (int j = 0; j < 4; ++j)
                        acc[i][j] = fmaf(av[i], bv[j], acc[i][j]);
            }
        }

        // dump tile scores to LDS
        #pragma unroll
        for (int i = 0; i < 4; ++i)
            #pragma unroll
            for (int j = 0; j < 4; ++j)
                sc[(ty << 2) + i][(tx << 2) + j] = acc[i][j];
        __syncthreads();

        // one owner thread per query scans the 64 scores in index order
        if (tid < BQ) {
            const int nv = min(tend - tb, BT);
            #pragma unroll 1
            for (int j = 0; j < nv; ++j) {
                const int tg = tb + j;
                const float d = fmaf(-2.0f, sc[tid][j], tsq[tg]);
                ins5(td, ti, d, tg);
            }
        }
        // next subtile's first __syncthreads (inside K loop) fences the scan
        // before xs/ts are rewritten; sc is rewritten only after a full
        // barriered K loop, so no extra sync is needed here.
    }

    if (tid < BQ) {
        const size_t base = ((size_t)(q0 + tid) * NCH + c) * KNN;
        #pragma unroll
        for (int i = 0; i < KNN; ++i) { wsd[base + i] = td[i]; wsi[base + i] = ti[i]; }
    }
}

// ---------- Phase 2: merge chunk partials, gather labels, mode ----------
__global__ void knn_reduce(const float* __restrict__ wsd, const int* __restrict__ wsi,
                           const int* __restrict__ labels, int* __restrict__ out)
{
    const int q = blockIdx.x * blockDim.x + threadIdx.x;
    if (q >= N_TEST) return;

    float td[KNN]; int ti[KNN];
    #pragma unroll
    for (int i = 0; i < KNN; ++i) { td[i] = INF; ti[i] = -1; }

    const size_t base = (size_t)q * NCH * KNN;
    // Chunks in ascending order; within a chunk the 5-list is (d, idx)-sorted,
    // so equal-d candidates always arrive in ascending index order -> strict '<'
    // insertion preserves lowest-index-wins ties.
    #pragma unroll 1
    for (int m = 0; m < NCH * KNN; ++m) {
        ins5(td, ti, wsd[base + m], wsi[base + m]);
    }

    int lab[KNN];
    #pragma unroll
    for (int i = 0; i < KNN; ++i) lab[i] = labels[ti[i]];

    // mode: most frequent label, smallest label on count ties
    int bestLabel = 0x7fffffff, bestCount = 0;
    #pragma unroll
    for (int i = 0; i < KNN; ++i) {
        int cnt = 0;
        #pragma unroll
        for (int j = 0; j < KNN; ++j) cnt += (lab[j] == lab[i]) ? 1 : 0;
        if (cnt > bestCount || (cnt == bestCount && lab[i] < bestLabel)) {
            bestCount = cnt; bestLabel = lab[i];
        }
    }
    out[q] = bestLabel;
}

extern "C" void kernel_launch(void* const* d_in, const int* in_sizes, int n_in,
                              void* d_out, int out_size, void* d_ws, size_t ws_size,
                              hipStream_t stream) {
    const float* x      = (const float*)d_in[0];
    const float* train  = (const float*)d_in[1];
    const int*   labels = (const int*)d_in[2];
    int* out = (int*)d_out;

    char* ws = (char*)d_ws;
    const size_t topk = (size_t)N_TEST * NCH * KNN;       // 327680 entries
    float* wsd = (float*)ws;                              // 1.31 MB
    int*   wsi = (int*)(ws + topk * 4);                   // 1.31 MB
    float* tsq = (float*)(ws + topk * 8);                 // 400 KB

    hipLaunchKernelGGL(tsq_kernel, dim3(512), dim3(256), 0, stream, train, tsq);
    hipLaunchKernelGGL(knn_partial, dim3(N_TEST / BQ, NCH), dim3(256), 0, stream,
                       x, train, tsq, wsd, wsi);
    hipLaunchKernelGGL(knn_reduce, dim3((N_TEST + 255) / 256), dim3(256), 0, stream,
                       wsd, wsi, labels, out);
}

// Round 2
// 1867.888 us; speedup vs baseline: 3.7439x; 3.7439x over previous
//
#include <hip/hip_runtime.h>

// kNN (K=5, 100 classes) via f16 hi/lo split MFMA GEMM.
// Rank by s = 1024*tsq[t] - 2*dot32(x,t), dot32 = (32x)·(32t) computed as
// hh + hl + lh with x32 = hi + lo (f16 Dekker split, scale 32 keeps lo normal).

#define N_TEST   4096
#define N_TRAIN  100000
#define DIM      512
#define KNN      5
#define NCH      32
#define TPC      3200          // trains per chunk = 25 tiles of 128
#define NKT      8             // 512 / BK,  BK = 64
#define INF      3.402823466e38f
#define IMAX     0x7fffffff

typedef __attribute__((ext_vector_type(8))) _Float16 f16x8;
typedef __attribute__((ext_vector_type(4))) _Float16 f16x4;
typedef __attribute__((ext_vector_type(4))) float    f32x4;

// ---- LDS byte offsets (one 66 KB arena) ----
#define AHI_OFF   0
#define ALO_OFF   16384
#define BHI_OFF   32768
#define BLO_OFF   49152
#define TSQ_OFF   65536
#define SMEM_SZ   66048
// merge region aliases [0, 40960): md[128][40] f32 @0, mi[128][40] i32 @20480

__device__ __forceinline__ int swz(int row, int kb) {
    return row * 128 + (kb ^ ((row & 7) << 4));
}

// strict-< on d (callers guarantee ascending-index arrival order)
__device__ __forceinline__ void ins5(float (&td)[KNN], int (&ti)[KNN], float d, int tg) {
    if (d < td[4]) {
        if (d < td[3]) {
            td[4] = td[3]; ti[4] = ti[3];
            if (d < td[2]) {
                td[3] = td[2]; ti[3] = ti[2];
                if (d < td[1]) {
                    td[2] = td[1]; ti[2] = ti[1];
                    if (d < td[0]) {
                        td[1] = td[0]; ti[1] = ti[0];
                        td[0] = d; ti[0] = tg;
                    } else { td[1] = d; ti[1] = tg; }
                } else { td[2] = d; ti[2] = tg; }
            } else { td[3] = d; ti[3] = tg; }
        } else { td[4] = d; ti[4] = tg; }
    }
}

__device__ __forceinline__ bool bet(float d, int t, float dd, int tt) {
    return (d < dd) || (d == dd && t < tt);
}

// lexicographic (d, idx) insertion — order-independent tie handling
__device__ __forceinline__ void ins5lex(float (&td)[KNN], int (&ti)[KNN], float d, int tg) {
    if (bet(d, tg, td[4], ti[4])) {
        if (bet(d, tg, td[3], ti[3])) {
            td[4] = td[3]; ti[4] = ti[3];
            if (bet(d, tg, td[2], ti[2])) {
                td[3] = td[2]; ti[3] = ti[2];
                if (bet(d, tg, td[1], ti[1])) {
                    td[2] = td[1]; ti[2] = ti[1];
                    if (bet(d, tg, td[0], ti[0])) {
                        td[1] = td[0]; ti[1] = ti[0];
                        td[0] = d; ti[0] = tg;
                    } else { td[1] = d; ti[1] = tg; }
                } else { td[2] = d; ti[2] = tg; }
            } else { td[3] = d; ti[3] = tg; }
        } else { td[4] = d; ti[4] = tg; }
    }
}

// ---------------- tsq[t] = 1024 * sum_k train[t][k]^2 ----------------
__global__ void tsq_kernel(const float* __restrict__ train, float* __restrict__ tsq) {
    const int lane = threadIdx.x & 63;
    const int wid  = (blockIdx.x * blockDim.x + threadIdx.x) >> 6;
    const int nw   = (gridDim.x * blockDim.x) >> 6;
    for (int row = wid; row < N_TRAIN; row += nw) {
        const float4* p = (const float4*)(train + (size_t)row * DIM);
        float4 a = p[lane];
        float4 b = p[lane + 64];
        float s = a.x*a.x + a.y*a.y + a.z*a.z + a.w*a.w
                + b.x*b.x + b.y*b.y + b.z*b.z + b.w*b.w;
        #pragma unroll
        for (int off = 32; off > 0; off >>= 1) s += __shfl_down(s, off, 64);
        if (lane == 0) tsq[row] = s * 1024.0f;
    }
}

// ---------------- x -> hi/lo f16 split of 32*x ----------------
__global__ void xsplit_kernel(const float* __restrict__ x,
                              _Float16* __restrict__ xhi, _Float16* __restrict__ xlo) {
    const int i = blockIdx.x * blockDim.x + threadIdx.x;   // one float4
    if (i >= N_TEST * DIM / 4) return;
    const float4 v = ((const float4*)x)[i];
    float f[4] = {v.x, v.y, v.z, v.w};
    f16x4 h, l;
    #pragma unroll
    for (int e = 0; e < 4; ++e) {
        const float s = f[e] * 32.0f;
        const _Float16 hh = (_Float16)s;
        h[e] = hh;
        l[e] = (_Float16)(s - (float)hh);
    }
    ((f16x4*)xhi)[i] = h;
    ((f16x4*)xlo)[i] = l;
}

// ---------------- fused split-GEMM + per-chunk top-5 ----------------
__global__ __launch_bounds__(256, 2) void knn_mfma(
    const float* __restrict__ train, const _Float16* __restrict__ xhi,
    const _Float16* __restrict__ xlo, const float* __restrict__ tsq,
    float* __restrict__ wsd, int* __restrict__ wsi)
{
    __shared__ __align__(16) char smem[SMEM_SZ];

    const int tid  = threadIdx.x;
    const int q0   = blockIdx.x * 128;
    const int c    = blockIdx.y;
    const int cstart = c * TPC;
    const int nt   = min(25, (N_TRAIN - cstart + 127) >> 7);

    const int w    = tid >> 6;
    const int wrow = w >> 1;          // train-half of tile
    const int wcol = w & 1;           // query-half of tile
    const int lane = tid & 63;
    const int l15  = lane & 15;
    const int lk   = lane >> 4;       // 0..3

    const int srow = tid >> 1;        // staging row 0..127
    const int sh   = tid & 1;         // staging k-half (32 floats)

    // per-lane top-5 lists for 4 queries (nj = 0..3)
    float td[4][KNN]; int ti[4][KNN];
    #pragma unroll
    for (int nj = 0; nj < 4; ++nj)
        #pragma unroll
        for (int j = 0; j < KNN; ++j) { td[nj][j] = INF; ti[nj][j] = IMAX; }

    for (int at = 0; at < nt; ++at) {
        const int tbase = cstart + at * 128;

        f32x4 acc[4][4];
        #pragma unroll
        for (int mi = 0; mi < 4; ++mi)
            #pragma unroll
            for (int nj = 0; nj < 4; ++nj) acc[mi][nj] = (f32x4){0.f, 0.f, 0.f, 0.f};

        for (int kt = 0; kt < NKT; ++kt) {
            // ---- issue global loads ----
            const int trow_g = min(tbase + srow, N_TRAIN - 1);
            const float* gpa = train + (size_t)trow_g * DIM + kt * 64 + sh * 32;
            float4 av[8];
            #pragma unroll
            for (int j = 0; j < 8; ++j) av[j] = ((const float4*)gpa)[j];

            const size_t bofs = (size_t)(q0 + srow) * DIM + kt * 64 + sh * 32;
            f16x8 bh[4], bl[4];
            #pragma unroll
            for (int j = 0; j < 4; ++j) {
                bh[j] = ((const f16x8*)(xhi + bofs))[j];
                bl[j] = ((const f16x8*)(xlo + bofs))[j];
            }
            float tq = 0.0f;
            if (kt == 0 && tid < 128) tq = tsq[min(tbase + tid, N_TRAIN - 1)];

            __syncthreads();   // previous iteration's LDS reads complete

            // ---- convert A + write LDS (swizzled) ----
            #pragma unroll
            for (int j = 0; j < 4; ++j) {
                f16x8 h, l;
                const float4 v0 = av[2*j], v1 = av[2*j+1];
                const float fv[8] = {v0.x, v0.y, v0.z, v0.w, v1.x, v1.y, v1.z, v1.w};
                #pragma unroll
                for (int e = 0; e < 8; ++e) {
                    const float s = fv[e] * 32.0f;
                    const _Float16 hh = (_Float16)s;
                    h[e] = hh;
                    l[e] = (_Float16)(s - (float)hh);
                }
                const int kb = sh * 64 + j * 16;
                *(f16x8*)(smem + AHI_OFF + swz(srow, kb)) = h;
                *(f16x8*)(smem + ALO_OFF + swz(srow, kb)) = l;
                *(f16x8*)(smem + BHI_OFF + swz(srow, kb)) = bh[j];
                *(f16x8*)(smem + BLO_OFF + swz(srow, kb)) = bl[j];
            }
            if (kt == 0 && tid < 128) ((float*)(smem + TSQ_OFF))[tid] = tq;

            __syncthreads();

            // ---- MFMA: 2 k-steps of 32 ----
            #pragma unroll
            for (int kk = 0; kk < 2; ++kk) {
                const int kb = kk * 64 + lk * 16;
                f16x8 vbh[4], vbl[4];
                #pragma unroll
                for (int nj = 0; nj < 4; ++nj) {
                    const int bc = wcol * 64 + nj * 16 + l15;
                    vbh[nj] = *(const f16x8*)(smem + BHI_OFF + swz(bc, kb));
                    vbl[nj] = *(const f16x8*)(smem + BLO_OFF + swz(bc, kb));
                }
                #pragma unroll
                for (int mi = 0; mi < 4; ++mi) {
                    const int ar = wrow * 64 + mi * 16 + l15;
                    const f16x8 ah = *(const f16x8*)(smem + AHI_OFF + swz(ar, kb));
                    const f16x8 al = *(const f16x8*)(smem + ALO_OFF + swz(ar, kb));
                    #pragma unroll
                    for (int nj = 0; nj < 4; ++nj) {
                        acc[mi][nj] = __builtin_amdgcn_mfma_f32_16x16x32_f16(ah, vbh[nj], acc[mi][nj], 0, 0, 0);
                        acc[mi][nj] = __builtin_amdgcn_mfma_f32_16x16x32_f16(ah, vbl[nj], acc[mi][nj], 0, 0, 0);
                        acc[mi][nj] = __builtin_amdgcn_mfma_f32_16x16x32_f16(al, vbh[nj], acc[mi][nj], 0, 0, 0);
                    }
                }
            }
        }

        // ---- epilogue: scores + per-lane top-5 (ascending t per list) ----
        const float* tsqs = (const float*)(smem + TSQ_OFF);
        #pragma unroll
        for (int nj = 0; nj < 4; ++nj) {
            #pragma unroll
            for (int mi = 0; mi < 4; ++mi) {
                const int tloc = wrow * 64 + mi * 16 + lk * 4;
                #pragma unroll
                for (int r = 0; r < 4; ++r) {
                    const int tg = tbase + tloc + r;
                    if (tg < N_TRAIN) {
                        const float d = fmaf(-2.0f, acc[mi][nj][r], tsqs[tloc + r]);
                        ins5(td[nj], ti[nj], d, tg);
                    }
                }
            }
        }
    }

    // ---- block-level merge: 8 lists per query -> top-5 -> ws ----
    __syncthreads();   // all LDS use done; reuse arena
    float* md  = (float*)(smem);
    int*   mi_ = (int*)(smem + 20480);
    #pragma unroll
    for (int nj = 0; nj < 4; ++nj) {
        const int ql   = wcol * 64 + nj * 16 + l15;
        const int slot = wrow * 4 + lk;
        #pragma unroll
        for (int j = 0; j < KNN; ++j) {
            md [(ql * 8 + slot) * KNN + j] = td[nj][j];
            mi_[(ql * 8 + slot) * KNN + j] = ti[nj][j];
        }
    }
    __syncthreads();
    if (tid < 128) {
        float fd[KNN]; int fi[KNN];
        #pragma unroll
        for (int j = 0; j < KNN; ++j) { fd[j] = INF; fi[j] = IMAX; }
        #pragma unroll 1
        for (int s = 0; s < 40; ++s)
            ins5lex(fd, fi, md[tid * 40 + s], mi_[tid * 40 + s]);
        const size_t base = ((size_t)(q0 + tid) * NCH + c) * KNN;
        #pragma unroll
        for (int j = 0; j < KNN; ++j) { wsd[base + j] = fd[j]; wsi[base + j] = fi[j]; }
    }
}

// ---------- merge chunk partials, gather labels, mode ----------
__global__ void knn_reduce(const float* __restrict__ wsd, const int* __restrict__ wsi,
                           const int* __restrict__ labels, int* __restrict__ out)
{
    const int q = blockIdx.x * blockDim.x + threadIdx.x;
    if (q >= N_TEST) return;

    float td[KNN]; int ti[KNN];
    #pragma unroll
    for (int i = 0; i < KNN; ++i) { td[i] = INF; ti[i] = IMAX; }

    const size_t base = (size_t)q * NCH * KNN;
    #pragma unroll 1
    for (int m = 0; m < NCH * KNN; ++m)
        ins5lex(td, ti, wsd[base + m], wsi[base + m]);

    int lab[KNN];
    #pragma unroll
    for (int i = 0; i < KNN; ++i) lab[i] = labels[ti[i]];

    int bestLabel = IMAX, bestCount = 0;
    #pragma unroll
    for (int i = 0; i < KNN; ++i) {
        int cnt = 0;
        #pragma unroll
        for (int j = 0; j < KNN; ++j) cnt += (lab[j] == lab[i]) ? 1 : 0;
        if (cnt > bestCount || (cnt == bestCount && lab[i] < bestLabel)) {
            bestCount = cnt; bestLabel = lab[i];
        }
    }
    out[q] = bestLabel;
}

extern "C" void kernel_launch(void* const* d_in, const int* in_sizes, int n_in,
                              void* d_out, int out_size, void* d_ws, size_t ws_size,
                              hipStream_t stream) {
    const float* x      = (const float*)d_in[0];
    const float* train  = (const float*)d_in[1];
    const int*   labels = (const int*)d_in[2];
    int* out = (int*)d_out;

    char* ws = (char*)d_ws;
    float*    wsd = (float*)(ws);                       // 2,621,440 B
    int*      wsi = (int*)(ws + 2621440);               // 2,621,440 B
    float*    tsq = (float*)(ws + 5242880);             //   400,000 B (padded region 401,408)
    _Float16* xhi = (_Float16*)(ws + 5644288);          // 4,194,304 B
    _Float16* xlo = (_Float16*)(ws + 9838592);          // 4,194,304 B  -> total ~13.4 MiB

    hipLaunchKernelGGL(tsq_kernel, dim3(512), dim3(256), 0, stream, train, tsq);
    hipLaunchKernelGGL(xsplit_kernel, dim3(N_TEST * DIM / 4 / 256), dim3(256), 0, stream,
                       x, xhi, xlo);
    hipLaunchKernelGGL(knn_mfma, dim3(N_TEST / 128, NCH), dim3(256), 0, stream,
                       train, xhi, xlo, tsq, wsd, wsi);
    hipLaunchKernelGGL(knn_reduce, dim3((N_TEST + 255) / 256), dim3(256), 0, stream,
                       wsd, wsi, labels, out);
}

// Round 3
// 1602.441 us; speedup vs baseline: 4.3641x; 1.1657x over previous
//
#include <hip/hip_runtime.h>

// kNN (K=5, 100 classes), two-stage:
//   Stage A: f16 MFMA GEMM (approx scores s~ = tsq - 2*dot16), per-chunk top-8
//            candidates per query (16 chunks x 8 = 128 candidates).
//   Stage B: exact fp32 rescore of 128 candidates -> top-5 (lex (d,idx)) ->
//            label mode (smallest label on count ties).

#define N_TEST   4096
#define N_TRAIN  100000
#define DIM      512
#define KNN      5
#define NCH      16
#define TPC      6400          // trains per chunk = 50 tiles of 128
#define TD8      8             // candidate depth per (query, chunk)
#define INF      3.402823466e38f
#define IMAX     0x7fffffff

typedef __attribute__((ext_vector_type(8))) _Float16 f16x8;
typedef __attribute__((ext_vector_type(4))) _Float16 f16x4;
typedef __attribute__((ext_vector_type(4))) float    f32x4;

// LDS arena (knn_approx): A f16 [0,16K), B f16 [16K,32K), tsq [32K, 32K+512)
#define A_OFF    0
#define B_OFF    16384
#define TSQ_OFF  32768
#define SMEM_SZ  33280
// merge aliases: md f32 [8][8][64] @0 (16K), mI i32 [8][8][64] @16384 (16K)

__device__ __forceinline__ int swz(int row, int kb) {
    return row * 128 + (kb ^ ((row & 7) << 4));
}

__device__ __forceinline__ bool bet(float d, int t, float dd, int tt) {
    return (d < dd) || (d == dd && t < tt);
}

// top-8, strict-< on d; callers feed candidates in ascending train index.
__device__ __forceinline__ void ins8(float (&td)[TD8], int (&ti)[TD8], float d, int tg) {
    if (d < td[TD8 - 1]) {
        td[TD8 - 1] = d; ti[TD8 - 1] = tg;
        #pragma unroll
        for (int j = TD8 - 1; j > 0; --j) {
            if (td[j] < td[j - 1]) {
                float t0 = td[j]; td[j] = td[j - 1]; td[j - 1] = t0;
                int   i0 = ti[j]; ti[j] = ti[j - 1]; ti[j - 1] = i0;
            }
        }
    }
}

// top-8 lexicographic (d, idx) — order-independent
__device__ __forceinline__ void ins8lex(float (&td)[TD8], int (&ti)[TD8], float d, int tg) {
    if (bet(d, tg, td[TD8 - 1], ti[TD8 - 1])) {
        td[TD8 - 1] = d; ti[TD8 - 1] = tg;
        #pragma unroll
        for (int j = TD8 - 1; j > 0; --j) {
            if (bet(td[j], ti[j], td[j - 1], ti[j - 1])) {
                float t0 = td[j]; td[j] = td[j - 1]; td[j - 1] = t0;
                int   i0 = ti[j]; ti[j] = ti[j - 1]; ti[j - 1] = i0;
            }
        }
    }
}

// top-5 lexicographic chain (proven in R2)
__device__ __forceinline__ void ins5lex(float (&td)[KNN], int (&ti)[KNN], float d, int tg) {
    if (bet(d, tg, td[4], ti[4])) {
        if (bet(d, tg, td[3], ti[3])) {
            td[4] = td[3]; ti[4] = ti[3];
            if (bet(d, tg, td[2], ti[2])) {
                td[3] = td[2]; ti[3] = ti[2];
                if (bet(d, tg, td[1], ti[1])) {
                    td[2] = td[1]; ti[2] = ti[1];
                    if (bet(d, tg, td[0], ti[0])) {
                        td[1] = td[0]; ti[1] = ti[0];
                        td[0] = d; ti[0] = tg;
                    } else { td[1] = d; ti[1] = tg; }
                } else { td[2] = d; ti[2] = tg; }
            } else { td[3] = d; ti[3] = tg; }
        } else { td[4] = d; ti[4] = tg; }
    }
}

// ---------------- tsq[t] = sum_k train[t][k]^2 (plain fp32) ----------------
__global__ void tsq_kernel(const float* __restrict__ train, float* __restrict__ tsq) {
    const int lane = threadIdx.x & 63;
    const int wid  = (blockIdx.x * blockDim.x + threadIdx.x) >> 6;
    const int nw   = (gridDim.x * blockDim.x) >> 6;
    for (int row = wid; row < N_TRAIN; row += nw) {
        const float4* p = (const float4*)(train + (size_t)row * DIM);
        float4 a = p[lane];
        float4 b = p[lane + 64];
        float s = a.x*a.x + a.y*a.y + a.z*a.z + a.w*a.w
                + b.x*b.x + b.y*b.y + b.z*b.z + b.w*b.w;
        #pragma unroll
        for (int off = 32; off > 0; off >>= 1) s += __shfl_down(s, off, 64);
        if (lane == 0) tsq[row] = s;
    }
}

// ---------------- x -> f16 ----------------
__global__ void xconv_kernel(const float* __restrict__ x, _Float16* __restrict__ xf) {
    const int i = blockIdx.x * blockDim.x + threadIdx.x;   // one float4
    if (i >= N_TEST * DIM / 4) return;
    const float4 v = ((const float4*)x)[i];
    f16x4 h;
    h[0] = (_Float16)v.x; h[1] = (_Float16)v.y;
    h[2] = (_Float16)v.z; h[3] = (_Float16)v.w;
    ((f16x4*)xf)[i] = h;
}

// -------- Stage A: f16 GEMM + per-(query,chunk) top-8 candidates --------
__global__ __launch_bounds__(256, 2) void knn_approx(
    const float* __restrict__ train, const _Float16* __restrict__ xf,
    const float* __restrict__ tsq,
    float* __restrict__ wsd, int* __restrict__ wsi)
{
    __shared__ __align__(16) char smem[SMEM_SZ];

    const int tid  = threadIdx.x;
    const int q0   = blockIdx.x * 128;
    const int c    = blockIdx.y;
    const int cstart = c * TPC;
    const int nt   = min(TPC >> 7, (N_TRAIN - cstart + 127) >> 7);

    const int w    = tid >> 6;
    const int wrow = w >> 1;          // train-half
    const int wcol = w & 1;           // query-half
    const int lane = tid & 63;
    const int l15  = lane & 15;
    const int lk   = lane >> 4;       // 0..3

    const int srow = tid >> 1;        // staging row 0..127
    const int sh   = tid & 1;         // staging k-half (32 elems)

    float td[4][TD8]; int ti[4][TD8];
    #pragma unroll
    for (int nj = 0; nj < 4; ++nj)
        #pragma unroll
        for (int j = 0; j < TD8; ++j) { td[nj][j] = INF; ti[nj][j] = IMAX; }

    for (int at = 0; at < nt; ++at) {
        const int tbase = cstart + at * 128;

        f32x4 acc[4][4];
        #pragma unroll
        for (int mi = 0; mi < 4; ++mi)
            #pragma unroll
            for (int nj = 0; nj < 4; ++nj) acc[mi][nj] = (f32x4){0.f, 0.f, 0.f, 0.f};

        // prologue: load kt=0 into regs
        const int trow_g = min(tbase + srow, N_TRAIN - 1);
        const float*  gA = train + (size_t)trow_g * DIM + sh * 32;
        const _Float16* gB = xf + (size_t)(q0 + srow) * DIM + sh * 32;

        float4 av[8];
        f16x8  bv[4];
        #pragma unroll
        for (int j = 0; j < 8; ++j) av[j] = ((const float4*)gA)[j];
        #pragma unroll
        for (int j = 0; j < 4; ++j) bv[j] = ((const f16x8*)gB)[j];
        float tq = 0.0f;
        if (tid < 128) tq = tsq[min(tbase + tid, N_TRAIN - 1)];

        for (int kt = 0; kt < 8; ++kt) {
            __syncthreads();                    // prior LDS reads complete

            // convert A + write both tiles (swizzled)
            #pragma unroll
            for (int j = 0; j < 4; ++j) {
                const float4 v0 = av[2*j], v1 = av[2*j+1];
                const float fv[8] = {v0.x, v0.y, v0.z, v0.w, v1.x, v1.y, v1.z, v1.w};
                f16x8 h;
                #pragma unroll
                for (int e = 0; e < 8; ++e) h[e] = (_Float16)fv[e];
                const int kb = sh * 64 + j * 16;
                *(f16x8*)(smem + A_OFF + swz(srow, kb)) = h;
                *(f16x8*)(smem + B_OFF + swz(srow, kb)) = bv[j];
            }
            if (kt == 0 && tid < 128) ((float*)(smem + TSQ_OFF))[tid] = tq;

            __syncthreads();

            // prefetch kt+1 (in flight across the MFMA section)
            if (kt < 7) {
                const float*    pA = gA + (kt + 1) * 64;
                const _Float16* pB = gB + (kt + 1) * 64;
                #pragma unroll
                for (int j = 0; j < 8; ++j) av[j] = ((const float4*)pA)[j];
                #pragma unroll
                for (int j = 0; j < 4; ++j) bv[j] = ((const f16x8*)pB)[j];
            }

            // MFMA: K=64 as 2 k-steps of 32
            #pragma unroll
            for (int kk = 0; kk < 2; ++kk) {
                const int kb = kk * 64 + lk * 16;
                f16x8 vb[4];
                #pragma unroll
                for (int nj = 0; nj < 4; ++nj)
                    vb[nj] = *(const f16x8*)(smem + B_OFF + swz(wcol * 64 + nj * 16 + l15, kb));
                #pragma unroll
                for (int mi = 0; mi < 4; ++mi) {
                    const f16x8 ah = *(const f16x8*)(smem + A_OFF + swz(wrow * 64 + mi * 16 + l15, kb));
                    #pragma unroll
                    for (int nj = 0; nj < 4; ++nj)
                        acc[mi][nj] = __builtin_amdgcn_mfma_f32_16x16x32_f16(ah, vb[nj], acc[mi][nj], 0, 0, 0);
                }
            }
        }

        // epilogue: approx scores -> per-lane top-8 (ascending index order)
        const float* tsqs = (const float*)(smem + TSQ_OFF);
        #pragma unroll
        for (int nj = 0; nj < 4; ++nj) {
            #pragma unroll
            for (int mi = 0; mi < 4; ++mi) {
                const int tloc = wrow * 64 + mi * 16 + lk * 4;
                #pragma unroll
                for (int r = 0; r < 4; ++r) {
                    const int tg = tbase + tloc + r;
                    if (tg < N_TRAIN) {
                        const float d = fmaf(-2.0f, acc[mi][nj][r], tsqs[tloc + r]);
                        ins8(td[nj], ti[nj], d, tg);
                    }
                }
            }
        }
    }

    // ---- block merge: 8 lists/query -> top-8/ (query,chunk) -> ws ----
    // two rounds of 64 queries; md [slot][depth][qr] layout (conflict-free)
    __syncthreads();
    float* md = (float*)(smem);
    int*   mI = (int*)(smem + 16384);
    for (int half = 0; half < 2; ++half) {
        if (half) __syncthreads();
        #pragma unroll
        for (int p = 0; p < 2; ++p) {
            const int nj   = half * 2 + p;
            const int qr   = wcol * 32 + p * 16 + l15;
            const int slot = wrow * 4 + lk;
            #pragma unroll
            for (int j = 0; j < TD8; ++j) {
                md[(slot * TD8 + j) * 64 + qr] = td[nj][j];
                mI[(slot * TD8 + j) * 64 + qr] = ti[nj][j];
            }
        }
        __syncthreads();
        if (tid < 64) {
            const int qr = tid;
            float fd[TD8]; int fi[TD8];
            #pragma unroll
            for (int j = 0; j < TD8; ++j) { fd[j] = INF; fi[j] = IMAX; }
            #pragma unroll 1
            for (int s = 0; s < 64; ++s)
                ins8lex(fd, fi, md[s * 64 + qr], mI[s * 64 + qr]);
            const int q = q0 + (qr >> 5) * 64 + (half * 2 + ((qr >> 4) & 1)) * 16 + (qr & 15);
            const size_t base = ((size_t)q * NCH + c) * TD8;
            #pragma unroll
            for (int j = 0; j < TD8; ++j) { wsd[base + j] = fd[j]; wsi[base + j] = fi[j]; }
        }
    }
}

// -------- Stage B: exact fp32 rescore of 128 candidates + mode --------
__global__ __launch_bounds__(256) void knn_final(
    const float* __restrict__ x, const float* __restrict__ train,
    const float* __restrict__ tsq, const int* __restrict__ wsi,
    const int* __restrict__ labels, int* __restrict__ out)
{
    __shared__ float sc[128];
    __shared__ int   ci[128];

    const int q    = blockIdx.x;
    const int tid  = threadIdx.x;
    const int lane = tid & 63;
    const int w    = tid >> 6;

    // x row: each lane holds 8 floats
    const float4* xp = (const float4*)(x + (size_t)q * DIM);
    const float4 xa = xp[lane * 2], xb = xp[lane * 2 + 1];

    if (tid < 128) ci[tid] = wsi[(size_t)q * (NCH * TD8) + tid];
    __syncthreads();

    #pragma unroll 1
    for (int it = 0; it < 32; ++it) {
        const int cidx = w * 32 + it;
        const int t = ci[cidx];
        const float4* tp = (const float4*)(train + (size_t)t * DIM);
        const float4 ta = tp[lane * 2], tb = tp[lane * 2 + 1];
        float s = ta.x*xa.x + ta.y*xa.y + ta.z*xa.z + ta.w*xa.w
                + tb.x*xb.x + tb.y*xb.y + tb.z*xb.z + tb.w*xb.w;
        #pragma unroll
        for (int off = 32; off > 0; off >>= 1) s += __shfl_down(s, off, 64);
        if (lane == 0) sc[cidx] = fmaf(-2.0f, s, tsq[t]);
    }
    __syncthreads();

    if (tid == 0) {
        float fd[KNN]; int fi[KNN];
        #pragma unroll
        for (int j = 0; j < KNN; ++j) { fd[j] = INF; fi[j] = IMAX; }
        #pragma unroll 1
        for (int s = 0; s < 128; ++s) ins5lex(fd, fi, sc[s], ci[s]);

        int lab[KNN];
        #pragma unroll
        for (int i = 0; i < KNN; ++i) lab[i] = labels[fi[i]];

        int bestLabel = IMAX, bestCount = 0;
        #pragma unroll
        for (int i = 0; i < KNN; ++i) {
            int cnt = 0;
            #pragma unroll
            for (int j = 0; j < KNN; ++j) cnt += (lab[j] == lab[i]) ? 1 : 0;
            if (cnt > bestCount || (cnt == bestCount && lab[i] < bestLabel)) {
                bestCount = cnt; bestLabel = lab[i];
            }
        }
        out[q] = bestLabel;
    }
}

extern "C" void kernel_launch(void* const* d_in, const int* in_sizes, int n_in,
                              void* d_out, int out_size, void* d_ws, size_t ws_size,
                              hipStream_t stream) {
    const float* x      = (const float*)d_in[0];
    const float* train  = (const float*)d_in[1];
    const int*   labels = (const int*)d_in[2];
    int* out = (int*)d_out;

    char* ws = (char*)d_ws;
    float*    wsd = (float*)(ws);                  // 4096*16*8*4 = 2,097,152
    int*      wsi = (int*)(ws + 2097152);          // 2,097,152
    float*    tsq = (float*)(ws + 4194304);        // 400,000 (pad to 401,408)
    _Float16* xf  = (_Float16*)(ws + 4595712);     // 4,194,304  -> total ~8.8 MB

    hipLaunchKernelGGL(tsq_kernel, dim3(512), dim3(256), 0, stream, train, tsq);
    hipLaunchKernelGGL(xconv_kernel, dim3(N_TEST * DIM / 4 / 256), dim3(256), 0, stream, x, xf);
    hipLaunchKernelGGL(knn_approx, dim3(N_TEST / 128, NCH), dim3(256), 0, stream,
                       train, xf, tsq, wsd, wsi);
    hipLaunchKernelGGL(knn_final, dim3(N_TEST), dim3(256), 0, stream,
                       x, train, tsq, wsi, labels, out);
}

// Round 4
// 1039.339 us; speedup vs baseline: 6.7285x; 1.5418x over previous
//
#include <hip/hip_runtime.h>

// kNN (K=5, 100 classes), two-stage:
//   convA/convB: f32 -> f16 pre-swizzled LDS-image layout (+ fused tsq)
//   knn_dma:     f16 MFMA GEMM, global_load_lds staging, 2-phase dbuf,
//                per-(query,chunk) top-8 candidates
//   knn_final:   exact fp32 rescore of 128 candidates -> top-5 -> mode
// Fallback (small ws): R3 pipeline (in-loop convert).

#define N_TEST   4096
#define N_TRAIN  100000
#define NPAD     100096      // 782*128
#define NTILE    782
#define DIM      512
#define KNN      5
#define NCH      16
#define TD8      8
#define INF      3.402823466e38f
#define IMAX     0x7fffffff

typedef __attribute__((ext_vector_type(8))) _Float16 f16x8;
typedef __attribute__((ext_vector_type(4))) _Float16 f16x4;
typedef __attribute__((ext_vector_type(4))) float    f32x4;

// ---- ws layout (DMA path) ----
#define WS_WSD   0u
#define WS_WSI   2097152u
#define WS_TSQ   4194304u
#define WS_AIMG  4595712u            // 782*8*16384 = 102,498,304
#define WS_BIMG  107094016u          // 32*8*16384  =   4,194,304
#define WS_NEED  111288320u
// fallback layout: wsd@0, wsi@2097152, tsq@4194304, xf@4595712 (+4,194,304)

__device__ __forceinline__ int swz(int row, int kb) {
    return row * 128 + (kb ^ ((row & 7) << 4));
}

__device__ __forceinline__ void gload_lds16(const void* g, void* l) {
    __builtin_amdgcn_global_load_lds(
        (const __attribute__((address_space(1))) void*)g,
        (__attribute__((address_space(3))) void*)l, 16, 0, 0);
}
__device__ __forceinline__ void gload_lds4(const void* g, void* l) {
    __builtin_amdgcn_global_load_lds(
        (const __attribute__((address_space(1))) void*)g,
        (__attribute__((address_space(3))) void*)l, 4, 0, 0);
}

__device__ __forceinline__ bool bet(float d, int t, float dd, int tt) {
    return (d < dd) || (d == dd && t < tt);
}

__device__ __forceinline__ void ins8(float (&td)[TD8], int (&ti)[TD8], float d, int tg) {
    if (d < td[TD8 - 1]) {
        td[TD8 - 1] = d; ti[TD8 - 1] = tg;
        #pragma unroll
        for (int j = TD8 - 1; j > 0; --j) {
            if (td[j] < td[j - 1]) {
                float t0 = td[j]; td[j] = td[j - 1]; td[j - 1] = t0;
                int   i0 = ti[j]; ti[j] = ti[j - 1]; ti[j - 1] = i0;
            }
        }
    }
}

__device__ __forceinline__ void ins8lex(float (&td)[TD8], int (&ti)[TD8], float d, int tg) {
    if (bet(d, tg, td[TD8 - 1], ti[TD8 - 1])) {
        td[TD8 - 1] = d; ti[TD8 - 1] = tg;
        #pragma unroll
        for (int j = TD8 - 1; j > 0; --j) {
            if (bet(td[j], ti[j], td[j - 1], ti[j - 1])) {
                float t0 = td[j]; td[j] = td[j - 1]; td[j - 1] = t0;
                int   i0 = ti[j]; ti[j] = ti[j - 1]; ti[j - 1] = i0;
            }
        }
    }
}

__device__ __forceinline__ void ins5lex(float (&td)[KNN], int (&ti)[KNN], float d, int tg) {
    if (bet(d, tg, td[4], ti[4])) {
        if (bet(d, tg, td[3], ti[3])) {
            td[4] = td[3]; ti[4] = ti[3];
            if (bet(d, tg, td[2], ti[2])) {
                td[3] = td[2]; ti[3] = ti[2];
                if (bet(d, tg, td[1], ti[1])) {
                    td[2] = td[1]; ti[2] = ti[1];
                    if (bet(d, tg, td[0], ti[0])) {
                        td[1] = td[0]; ti[1] = ti[0];
                        td[0] = d; ti[0] = tg;
                    } else { td[1] = d; ti[1] = tg; }
                } else { td[2] = d; ti[2] = tg; }
            } else { td[3] = d; ti[3] = tg; }
        } else { td[4] = d; ti[4] = tg; }
    }
}

// ================= conversion kernels (DMA path) =================
// one wave per padded row; lane j handles 8 elems -> one f16x8 image slot
__global__ __launch_bounds__(256) void convA_kernel(const float* __restrict__ train,
        char* __restrict__ Aimg, float* __restrict__ tsq) {
    const int w    = threadIdx.x >> 6;
    const int lane = threadIdx.x & 63;
    const int rp   = blockIdx.x * 4 + w;
    const int rs   = min(rp, N_TRAIN - 1);
    const float4* src = (const float4*)(train + (size_t)rs * DIM + lane * 8);
    const float4 v0 = src[0], v1 = src[1];
    const float fv[8] = {v0.x, v0.y, v0.z, v0.w, v1.x, v1.y, v1.z, v1.w};
    float s = 0.0f;
    f16x8 h;
    #pragma unroll
    for (int e = 0; e < 8; ++e) { s += fv[e] * fv[e]; h[e] = (_Float16)fv[e]; }
    #pragma unroll
    for (int off = 32; off > 0; off >>= 1) s += __shfl_down(s, off, 64);
    if (lane == 0 && rp < N_TRAIN) tsq[rp] = s;
    const int gt = rp >> 7, row = rp & 127, kt = lane >> 3, slot = lane & 7;
    *(f16x8*)(Aimg + ((size_t)(gt * 8 + kt)) * 16384 + swz(row, slot * 16)) = h;
}

__global__ __launch_bounds__(256) void convB_kernel(const float* __restrict__ x,
        char* __restrict__ Bimg) {
    const int w    = threadIdx.x >> 6;
    const int lane = threadIdx.x & 63;
    const int rp   = blockIdx.x * 4 + w;          // 0..4095
    const float4* src = (const float4*)(x + (size_t)rp * DIM + lane * 8);
    const float4 v0 = src[0], v1 = src[1];
    const float fv[8] = {v0.x, v0.y, v0.z, v0.w, v1.x, v1.y, v1.z, v1.w};
    f16x8 h;
    #pragma unroll
    for (int e = 0; e < 8; ++e) h[e] = (_Float16)fv[e];
    const int gt = rp >> 7, row = rp & 127, kt = lane >> 3, slot = lane & 7;
    *(f16x8*)(Bimg + ((size_t)(gt * 8 + kt)) * 16384 + swz(row, slot * 16)) = h;
}

// ================= Stage A (DMA path) =================
#define A0_ 0
#define A1_ 16384
#define B0_ 32768
#define B1_ 49152
#define TQ_ 65536
#define SM_SZ 66560

__global__ __launch_bounds__(256, 2) void knn_dma(
    const char* __restrict__ Aimg, const char* __restrict__ Bimg,
    const float* __restrict__ tsq,
    float* __restrict__ wsd, int* __restrict__ wsi)
{
    __shared__ __align__(16) char smem[SM_SZ];
    const int tid  = threadIdx.x;
    const int qt   = blockIdx.x;                // 0..31
    const int q0   = qt * 128;
    const int c    = blockIdx.y;                // 0..15
    const int gt0  = c * 50;
    const int nt   = min(50, NTILE - gt0);

    const int w    = tid >> 6;
    const int lane = tid & 63;
    const int wrow = w >> 1, wcol = w & 1;
    const int l15  = lane & 15, lk = lane >> 4;

    float td[4][TD8]; int ti[4][TD8];
    #pragma unroll
    for (int nj = 0; nj < 4; ++nj)
        #pragma unroll
        for (int j = 0; j < TD8; ++j) { td[nj][j] = INF; ti[nj][j] = IMAX; }

    auto stage = [&](int buf, int gt, int kt) {
        const char* asrc = Aimg + ((size_t)(gt * 8 + kt)) * 16384 + (size_t)(w * 4) * 1024 + lane * 16;
        const char* bsrc = Bimg + ((size_t)(qt * 8 + kt)) * 16384 + (size_t)(w * 4) * 1024 + lane * 16;
        char* adst = smem + (buf ? A1_ : A0_) + (w * 4) * 1024;
        char* bdst = smem + (buf ? B1_ : B0_) + (w * 4) * 1024;
        #pragma unroll
        for (int i = 0; i < 4; ++i) {
            gload_lds16(asrc + i * 1024, adst + i * 1024);
            gload_lds16(bsrc + i * 1024, bdst + i * 1024);
        }
    };
    auto stage_tsq = [&](int p, int tbase) {
        if (w == 0) {
            #pragma unroll
            for (int i = 0; i < 2; ++i) {
                const int idx = min(tbase + i * 64 + lane, N_TRAIN - 1);
                gload_lds4(tsq + idx, smem + TQ_ + p * 512 + i * 256);
            }
        }
    };

    stage(0, gt0, 0);
    stage_tsq(0, gt0 * 128);
    __syncthreads();
    int cur = 0;

    #pragma unroll 1
    for (int at = 0; at < nt; ++at) {
        const int gt    = gt0 + at;
        const int tbase = gt * 128;

        f32x4 acc[4][4];
        #pragma unroll
        for (int mi = 0; mi < 4; ++mi)
            #pragma unroll
            for (int nj = 0; nj < 4; ++nj) acc[mi][nj] = (f32x4){0.f, 0.f, 0.f, 0.f};

        #pragma unroll
        for (int kt = 0; kt < 8; ++kt) {
            // issue next-tile DMA (in flight under this kt's compute)
            if (kt < 7) stage(cur ^ 1, gt, kt + 1);
            else if (at + 1 < nt) { stage(cur ^ 1, gt + 1, 0); stage_tsq((at + 1) & 1, tbase + 128); }

            const int ab = cur ? A1_ : A0_;
            const int bb = cur ? B1_ : B0_;
            #pragma unroll
            for (int kk = 0; kk < 2; ++kk) {
                const int kb = kk * 64 + lk * 16;
                f16x8 vb[4];
                #pragma unroll
                for (int nj = 0; nj < 4; ++nj)
                    vb[nj] = *(const f16x8*)(smem + bb + swz(wcol * 64 + nj * 16 + l15, kb));
                #pragma unroll
                for (int mi = 0; mi < 4; ++mi) {
                    const f16x8 ah = *(const f16x8*)(smem + ab + swz(wrow * 64 + mi * 16 + l15, kb));
                    #pragma unroll
                    for (int nj = 0; nj < 4; ++nj)
                        acc[mi][nj] = __builtin_amdgcn_mfma_f32_16x16x32_f16(ah, vb[nj], acc[mi][nj], 0, 0, 0);
                }
            }

            if (kt == 7) {
                const float* tsqs = (const float*)(smem + TQ_ + (at & 1) * 512);
                #pragma unroll
                for (int nj = 0; nj < 4; ++nj) {
                    #pragma unroll
                    for (int mi = 0; mi < 4; ++mi) {
                        const int tloc = wrow * 64 + mi * 16 + lk * 4;
                        #pragma unroll
                        for (int r = 0; r < 4; ++r) {
                            const int tg = tbase + tloc + r;
                            if (tg < N_TRAIN) {
                                const float d = fmaf(-2.0f, acc[mi][nj][r], tsqs[tloc + r]);
                                ins8(td[nj], ti[nj], d, tg);
                            }
                        }
                    }
                }
            }
            __syncthreads();
            cur ^= 1;
        }
    }

    // ---- block merge: 8 lists/query -> top-8/(query,chunk) -> ws ----
    __syncthreads();
    float* md = (float*)(smem);
    int*   mI = (int*)(smem + 16384);
    for (int half = 0; half < 2; ++half) {
        if (half) __syncthreads();
        #pragma unroll
        for (int p = 0; p < 2; ++p) {
            const int nj   = half * 2 + p;
            const int qr   = wcol * 32 + p * 16 + l15;
            const int slot = wrow * 4 + lk;
            #pragma unroll
            for (int j = 0; j < TD8; ++j) {
                md[(slot * TD8 + j) * 64 + qr] = td[nj][j];
                mI[(slot * TD8 + j) * 64 + qr] = ti[nj][j];
            }
        }
        __syncthreads();
        if (tid < 64) {
            const int qr = tid;
            float fd[TD8]; int fi[TD8];
            #pragma unroll
            for (int j = 0; j < TD8; ++j) { fd[j] = INF; fi[j] = IMAX; }
            #pragma unroll 1
            for (int s = 0; s < 64; ++s)
                ins8lex(fd, fi, md[s * 64 + qr], mI[s * 64 + qr]);
            const int q = q0 + (qr >> 5) * 64 + (half * 2 + ((qr >> 4) & 1)) * 16 + (qr & 15);
            const size_t base = ((size_t)q * NCH + c) * TD8;
            #pragma unroll
            for (int j = 0; j < TD8; ++j) { wsd[base + j] = fd[j]; wsi[base + j] = fi[j]; }
        }
    }
}

// ================= fallback Stage A (R3, proven) =================
__global__ void tsq_kernel(const float* __restrict__ train, float* __restrict__ tsq) {
    const int lane = threadIdx.x & 63;
    const int wid  = (blockIdx.x * blockDim.x + threadIdx.x) >> 6;
    const int nw   = (gridDim.x * blockDim.x) >> 6;
    for (int row = wid; row < N_TRAIN; row += nw) {
        const float4* p = (const float4*)(train + (size_t)row * DIM);
        float4 a = p[lane];
        float4 b = p[lane + 64];
        float s = a.x*a.x + a.y*a.y + a.z*a.z + a.w*a.w
                + b.x*b.x + b.y*b.y + b.z*b.z + b.w*b.w;
        #pragma unroll
        for (int off = 32; off > 0; off >>= 1) s += __shfl_down(s, off, 64);
        if (lane == 0) tsq[row] = s;
    }
}

__global__ void xconv_kernel(const float* __restrict__ x, _Float16* __restrict__ xf) {
    const int i = blockIdx.x * blockDim.x + threadIdx.x;
    if (i >= N_TEST * DIM / 4) return;
    const float4 v = ((const float4*)x)[i];
    f16x4 h;
    h[0] = (_Float16)v.x; h[1] = (_Float16)v.y;
    h[2] = (_Float16)v.z; h[3] = (_Float16)v.w;
    ((f16x4*)xf)[i] = h;
}

#define FB_TPC 6400
__global__ __launch_bounds__(256, 2) void knn_approx(
    const float* __restrict__ train, const _Float16* __restrict__ xf,
    const float* __restrict__ tsq,
    float* __restrict__ wsd, int* __restrict__ wsi)
{
    __shared__ __align__(16) char smem[33280];
    const int tid  = threadIdx.x;
    const int q0   = blockIdx.x * 128;
    const int c    = blockIdx.y;
    const int cstart = c * FB_TPC;
    const int nt   = min(FB_TPC >> 7, (N_TRAIN - cstart + 127) >> 7);
    const int w    = tid >> 6;
    const int wrow = w >> 1, wcol = w & 1;
    const int lane = tid & 63;
    const int l15  = lane & 15, lk = lane >> 4;
    const int srow = tid >> 1, sh = tid & 1;

    float td[4][TD8]; int ti[4][TD8];
    #pragma unroll
    for (int nj = 0; nj < 4; ++nj)
        #pragma unroll
        for (int j = 0; j < TD8; ++j) { td[nj][j] = INF; ti[nj][j] = IMAX; }

    for (int at = 0; at < nt; ++at) {
        const int tbase = cstart + at * 128;
        f32x4 acc[4][4];
        #pragma unroll
        for (int mi = 0; mi < 4; ++mi)
            #pragma unroll
            for (int nj = 0; nj < 4; ++nj) acc[mi][nj] = (f32x4){0.f, 0.f, 0.f, 0.f};

        const int trow_g = min(tbase + srow, N_TRAIN - 1);
        const float*    gA = train + (size_t)trow_g * DIM + sh * 32;
        const _Float16* gB = xf + (size_t)(q0 + srow) * DIM + sh * 32;
        float4 av[8]; f16x8 bv[4];
        #pragma unroll
        for (int j = 0; j < 8; ++j) av[j] = ((const float4*)gA)[j];
        #pragma unroll
        for (int j = 0; j < 4; ++j) bv[j] = ((const f16x8*)gB)[j];
        float tq = 0.0f;
        if (tid < 128) tq = tsq[min(tbase + tid, N_TRAIN - 1)];

        for (int kt = 0; kt < 8; ++kt) {
            __syncthreads();
            #pragma unroll
            for (int j = 0; j < 4; ++j) {
                const float4 v0 = av[2*j], v1 = av[2*j+1];
                const float fv[8] = {v0.x, v0.y, v0.z, v0.w, v1.x, v1.y, v1.z, v1.w};
                f16x8 h;
                #pragma unroll
                for (int e = 0; e < 8; ++e) h[e] = (_Float16)fv[e];
                const int kb = sh * 64 + j * 16;
                *(f16x8*)(smem + 0     + swz(srow, kb)) = h;
                *(f16x8*)(smem + 16384 + swz(srow, kb)) = bv[j];
            }
            if (kt == 0 && tid < 128) ((float*)(smem + 32768))[tid] = tq;
            __syncthreads();
            if (kt < 7) {
                const float*    pA = gA + (kt + 1) * 64;
                const _Float16* pB = gB + (kt + 1) * 64;
                #pragma unroll
                for (int j = 0; j < 8; ++j) av[j] = ((const float4*)pA)[j];
                #pragma unroll
                for (int j = 0; j < 4; ++j) bv[j] = ((const f16x8*)pB)[j];
            }
            #pragma unroll
            for (int kk = 0; kk < 2; ++kk) {
                const int kb = kk * 64 + lk * 16;
                f16x8 vb[4];
                #pragma unroll
                for (int nj = 0; nj < 4; ++nj)
                    vb[nj] = *(const f16x8*)(smem + 16384 + swz(wcol * 64 + nj * 16 + l15, kb));
                #pragma unroll
                for (int mi = 0; mi < 4; ++mi) {
                    const f16x8 ah = *(const f16x8*)(smem + swz(wrow * 64 + mi * 16 + l15, kb));
                    #pragma unroll
                    for (int nj = 0; nj < 4; ++nj)
                        acc[mi][nj] = __builtin_amdgcn_mfma_f32_16x16x32_f16(ah, vb[nj], acc[mi][nj], 0, 0, 0);
                }
            }
        }
        const float* tsqs = (const float*)(smem + 32768);
        #pragma unroll
        for (int nj = 0; nj < 4; ++nj)
            #pragma unroll
            for (int mi = 0; mi < 4; ++mi) {
                const int tloc = wrow * 64 + mi * 16 + lk * 4;
                #pragma unroll
                for (int r = 0; r < 4; ++r) {
                    const int tg = tbase + tloc + r;
                    if (tg < N_TRAIN) {
                        const float d = fmaf(-2.0f, acc[mi][nj][r], tsqs[tloc + r]);
                        ins8(td[nj], ti[nj], d, tg);
                    }
                }
            }
    }

    __syncthreads();
    float* md = (float*)(smem);
    int*   mI = (int*)(smem + 16384);
    for (int half = 0; half < 2; ++half) {
        if (half) __syncthreads();
        #pragma unroll
        for (int p = 0; p < 2; ++p) {
            const int nj   = half * 2 + p;
            const int qr   = wcol * 32 + p * 16 + l15;
            const int slot = wrow * 4 + lk;
            #pragma unroll
            for (int j = 0; j < TD8; ++j) {
                md[(slot * TD8 + j) * 64 + qr] = td[nj][j];
                mI[(slot * TD8 + j) * 64 + qr] = ti[nj][j];
            }
        }
        __syncthreads();
        if (tid < 64) {
            const int qr = tid;
            float fd[TD8]; int fi[TD8];
            #pragma unroll
            for (int j = 0; j < TD8; ++j) { fd[j] = INF; fi[j] = IMAX; }
            #pragma unroll 1
            for (int s = 0; s < 64; ++s)
                ins8lex(fd, fi, md[s * 64 + qr], mI[s * 64 + qr]);
            const int q = q0 + (qr >> 5) * 64 + (half * 2 + ((qr >> 4) & 1)) * 16 + (qr & 15);
            const size_t base = ((size_t)q * NCH + c) * TD8;
            #pragma unroll
            for (int j = 0; j < TD8; ++j) { wsd[base + j] = fd[j]; wsi[base + j] = fi[j]; }
        }
    }
}

// ================= Stage B: exact rescore + mode =================
__global__ __launch_bounds__(256) void knn_final(
    const float* __restrict__ x, const float* __restrict__ train,
    const float* __restrict__ tsq, const int* __restrict__ wsi,
    const int* __restrict__ labels, int* __restrict__ out)
{
    __shared__ float sc[128];
    __shared__ int   ci[128];
    const int q    = blockIdx.x;
    const int tid  = threadIdx.x;
    const int lane = tid & 63;
    const int w    = tid >> 6;

    const float4* xp = (const float4*)(x + (size_t)q * DIM);
    const float4 xa = xp[lane * 2], xb = xp[lane * 2 + 1];

    if (tid < 128) ci[tid] = wsi[(size_t)q * (NCH * TD8) + tid];
    __syncthreads();

    #pragma unroll 1
    for (int it = 0; it < 32; ++it) {
        const int cidx = w * 32 + it;
        const int t = ci[cidx];
        const float4* tp = (const float4*)(train + (size_t)t * DIM);
        const float4 ta = tp[lane * 2], tb = tp[lane * 2 + 1];
        float s = ta.x*xa.x + ta.y*xa.y + ta.z*xa.z + ta.w*xa.w
                + tb.x*xb.x + tb.y*xb.y + tb.z*xb.z + tb.w*xb.w;
        #pragma unroll
        for (int off = 32; off > 0; off >>= 1) s += __shfl_down(s, off, 64);
        if (lane == 0) sc[cidx] = fmaf(-2.0f, s, tsq[t]);
    }
    __syncthreads();

    if (tid == 0) {
        float fd[KNN]; int fi[KNN];
        #pragma unroll
        for (int j = 0; j < KNN; ++j) { fd[j] = INF; fi[j] = IMAX; }
        #pragma unroll 1
        for (int s = 0; s < 128; ++s) ins5lex(fd, fi, sc[s], ci[s]);

        int lab[KNN];
        #pragma unroll
        for (int i = 0; i < KNN; ++i) lab[i] = labels[fi[i]];

        int bestLabel = IMAX, bestCount = 0;
        #pragma unroll
        for (int i = 0; i < KNN; ++i) {
            int cnt = 0;
            #pragma unroll
            for (int j = 0; j < KNN; ++j) cnt += (lab[j] == lab[i]) ? 1 : 0;
            if (cnt > bestCount || (cnt == bestCount && lab[i] < bestLabel)) {
                bestCount = cnt; bestLabel = lab[i];
            }
        }
        out[q] = bestLabel;
    }
}

extern "C" void kernel_launch(void* const* d_in, const int* in_sizes, int n_in,
                              void* d_out, int out_size, void* d_ws, size_t ws_size,
                              hipStream_t stream) {
    const float* x      = (const float*)d_in[0];
    const float* train  = (const float*)d_in[1];
    const int*   labels = (const int*)d_in[2];
    int* out = (int*)d_out;
    char* ws = (char*)d_ws;

    float* wsd = (float*)(ws + WS_WSD);
    int*   wsi = (int*)(ws + WS_WSI);
    float* tsq = (float*)(ws + WS_TSQ);

    if (ws_size >= (size_t)WS_NEED) {
        char* Aimg = ws + WS_AIMG;
        char* Bimg = ws + WS_BIMG;
        hipLaunchKernelGGL(convA_kernel, dim3(NPAD / 4), dim3(256), 0, stream, train, Aimg, tsq);
        hipLaunchKernelGGL(convB_kernel, dim3(N_TEST / 4), dim3(256), 0, stream, x, Bimg);
        hipLaunchKernelGGL(knn_dma, dim3(N_TEST / 128, NCH), dim3(256), 0, stream,
                           Aimg, Bimg, tsq, wsd, wsi);
    } else {
        _Float16* xf = (_Float16*)(ws + WS_AIMG);   // 4 MB slot in fallback
        hipLaunchKernelGGL(tsq_kernel, dim3(512), dim3(256), 0, stream, train, tsq);
        hipLaunchKernelGGL(xconv_kernel, dim3(N_TEST * DIM / 4 / 256), dim3(256), 0, stream, x, xf);
        hipLaunchKernelGGL(knn_approx, dim3(N_TEST / 128, NCH), dim3(256), 0, stream,
                           train, xf, tsq, wsd, wsi);
    }
    hipLaunchKernelGGL(knn_final, dim3(N_TEST), dim3(256), 0, stream,
                       x, train, tsq, wsi, labels, out);
}